// Round 6
// baseline (1154.057 us; speedup 1.0000x reference)
//
#include <hip/hip_runtime.h>

// Problem constants (fixed by reference)
#define H    256
#define HE   64
#define NPB  512         // nodes per batch
#define NA   512         // total anchors (8 batches * 64)
#define MU_STEP (20.0f / 63.0f)
#define INV_SIG 3.2f     // 1/0.3125
#define G_LD 384
#define NBLK 512

// workspace float offsets
#define OFF_G    0          // 320x384
#define OFF_QWT  122880     // [b][k][la] 8*256*64
#define OFF_QE   253952     // [a][j] 512*64
#define OFF_QBK  286720     // [a] 512 (pad 1024)
#define OFF_LGT  287744     // [b][n][la] 8*512*64
#define OFF_AF1  549888     // 512*256
#define OFF_M1   680960     // 512*512
#define OFF_M2   943104     // 512*512
#define OFF_Y3   1205248    // 512*256
#define OFF_KT   1336320    // [c][vrow] 320*256
#define OFF_W1T  1418240    // 256*512
#define OFF_W2T  1549312    // 512*512
#define OFF_W3T  1811456    // 512*256
#define OFF_BAR  1942528    // barrier: cnt, gen

// ---------------------------------------------------------------------------
__device__ __forceinline__ float wave_sum(float v) {
#pragma unroll
    for (int o = 32; o; o >>= 1) v += __shfl_xor(v, o, 64);
    return v;
}
__device__ __forceinline__ float wave_max(float v) {
#pragma unroll
    for (int o = 32; o; o >>= 1) v = fmaxf(v, __shfl_xor(v, o, 64));
    return v;
}
__device__ __forceinline__ float block_sum(float v, float* red4, int t) {
    v = wave_sum(v);
    if ((t & 63) == 0) red4[t >> 6] = v;
    __syncthreads();
    v = red4[0] + red4[1] + red4[2] + red4[3];
    __syncthreads();
    return v;
}
__device__ __forceinline__ float block_max(float v, float* red4, int t) {
    v = wave_max(v);
    if ((t & 63) == 0) red4[t >> 6] = v;
    __syncthreads();
    v = fmaxf(fmaxf(red4[0], red4[1]), fmaxf(red4[2], red4[3]));
    __syncthreads();
    return v;
}

// Grid barrier: arrive-count + generation, device scope, s_sleep backoff.
__device__ __forceinline__ void grid_sync(unsigned* cnt, unsigned* gen) {
    __syncthreads();
    if (threadIdx.x == 0) {
        __threadfence();   // release: write back dirty L2 (cross-XCD)
        unsigned g = __hip_atomic_load(gen, __ATOMIC_ACQUIRE, __HIP_MEMORY_SCOPE_AGENT);
        unsigned old = __hip_atomic_fetch_add(cnt, 1u, __ATOMIC_ACQ_REL, __HIP_MEMORY_SCOPE_AGENT);
        if (old == (unsigned)(NBLK - 1)) {
            __hip_atomic_store(cnt, 0u, __ATOMIC_RELAXED, __HIP_MEMORY_SCOPE_AGENT);
            __hip_atomic_store(gen, g + 1u, __ATOMIC_RELEASE, __HIP_MEMORY_SCOPE_AGENT);
        } else {
            while (__hip_atomic_load(gen, __ATOMIC_ACQUIRE, __HIP_MEMORY_SCOPE_AGENT) == g)
                __builtin_amdgcn_s_sleep(4);
        }
        __threadfence();   // acquire: invalidate L1/L2 before post-barrier reads
    }
    __syncthreads();
}

// ---------------------------------------------------------------------------
__global__ void __launch_bounds__(256, 2) mega_kernel(
    const float* __restrict__ anchor_x, const float* __restrict__ node_x,
    const float* __restrict__ anchor_f, const float* __restrict__ node_f,
    const float* __restrict__ node_mask,
    const float* __restrict__ Wq,  const float* __restrict__ bq,
    const float* __restrict__ Wkv, const float* __restrict__ bkv,
    const float* __restrict__ ln1_g, const float* __restrict__ ln1_b,
    const float* __restrict__ W1, const float* __restrict__ b1,
    const float* __restrict__ W2, const float* __restrict__ b2,
    const float* __restrict__ W3, const float* __restrict__ b3,
    const float* __restrict__ ln2_g, const float* __restrict__ ln2_b,
    float* __restrict__ ws, float* __restrict__ out)
{
    const int bid = blockIdx.x;
    const int t   = threadIdx.x;

    float* G      = ws + OFF_G;
    float* qWT    = ws + OFF_QWT;
    float* qe_ws  = ws + OFF_QE;
    float* qbk_ws = ws + OFF_QBK;
    float* lgT    = ws + OFF_LGT;
    float* af1    = ws + OFF_AF1;
    float* m1     = ws + OFF_M1;
    float* m2     = ws + OFF_M2;
    float* y3     = ws + OFF_Y3;
    float* KT     = ws + OFF_KT;
    float* W1T    = ws + OFF_W1T;
    float* W2T    = ws + OFF_W2T;
    float* W3T    = ws + OFF_W3T;
    unsigned* bar = (unsigned*)(ws + OFF_BAR);

    __shared__ __align__(16) float lds[8448];
    __shared__ int   lds_i[516];
    __shared__ float red4s[4];

    // ============ P0: weight transposes + G GEMM (blocks 0..177) ============
    if (bid < 178) {
        if (bid < 148) {
            float (*tile)[65] = (float(*)[65])lds;
            const float* src; float* dst; int C, Rd, tr, tc;
            if (bid < 32)       { src = W1; dst = W1T; C = 256; Rd = 512; tr = bid >> 2; tc = bid & 3; }
            else if (bid < 96)  { int ti = bid - 32; src = W2; dst = W2T; C = 512; Rd = 512; tr = ti >> 3; tc = ti & 7; }
            else if (bid < 128) { int ti = bid - 96; src = W3; dst = W3T; C = 512; Rd = 256; tr = ti >> 3; tc = ti & 7; }
            else                { int ti = bid - 128; src = Wkv + 256 * 320; dst = KT; C = 320; Rd = 256; tr = ti / 5; tc = ti % 5; }
            const int lane = t & 63, rg = t >> 6;
#pragma unroll
            for (int i = 0; i < 16; ++i) {
                int r = rg * 16 + i;
                tile[r][lane] = src[(size_t)(tr * 64 + r) * C + tc * 64 + lane];
            }
            __syncthreads();
#pragma unroll
            for (int i = 0; i < 16; ++i) {
                int r = rg * 16 + i;
                dst[(size_t)(tc * 64 + r) * Rd + tr * 64 + lane] = tile[lane][r];
            }
        } else {
            // G[j][n] = sum_o [Wq|bq][o][j] * [Wkv|bkv_k][o][n]
            float* Als = lds;            // [o][j] 64x64
            float* Bls = lds + 4096;     // [o][n] 64x64
            const int gb = bid - 148;    // 0..29  (5 j-tiles x 6 n-tiles)
            const int mt = gb / 6, nt = gb - mt * 6;
            const int m0 = mt * 64, n0 = nt * 64;
            const int nq = t & 15, mq = t >> 4;
            float acc[4][4];
#pragma unroll
            for (int i = 0; i < 4; ++i)
#pragma unroll
                for (int k = 0; k < 4; ++k) acc[i][k] = 0.f;
            for (int c0 = 0; c0 < 256; c0 += 64) {
                __syncthreads();
                for (int idx = t; idx < 4096; idx += 256) {
                    int cl = idx >> 6, el = idx & 63;
                    int c = c0 + cl;
                    int j = m0 + el;
                    Als[idx] = (j < 256) ? Wq[(size_t)c * 256 + j] : (j == 256 ? bq[c] : 0.f);
                    int n = n0 + el;
                    Bls[idx] = (n < 320) ? Wkv[(size_t)c * 320 + n] : (n == 320 ? bkv[c] : 0.f);
                }
                __syncthreads();
#pragma unroll 4
                for (int cl = 0; cl < 64; ++cl) {
                    const float* ar = Als + cl * 64 + mq * 4;
                    const float* br = Bls + cl * 64 + nq * 4;
#pragma unroll
                    for (int i = 0; i < 4; ++i)
#pragma unroll
                        for (int k = 0; k < 4; ++k)
                            acc[i][k] = fmaf(ar[i], br[k], acc[i][k]);
                }
            }
#pragma unroll
            for (int i = 0; i < 4; ++i) {
                int j = m0 + mq * 4 + i;
                float* gr = G + (size_t)j * G_LD + n0 + nq * 4;
                gr[0] = acc[i][0]; gr[1] = acc[i][1];
                gr[2] = acc[i][2]; gr[3] = acc[i][3];
            }
        }
    }
    grid_sync(bar, bar + 1);

    // ============ P1: anchor GEMM  [qW|qe|qbk] = AF @ G + G[256,:] ==========
    if (bid < 48) {                       // 8 m-tiles x 6 n-tiles
        float* Als = lds;                 // [m][c] 64x65 padded
        float* Bls = lds + 4160;          // [c][n] 64x65 padded
        const int mt = bid / 6, nt = bid - mt * 6;
        const int m0 = mt * 64, n0 = nt * 64;
        const int nq = t & 15, mq = t >> 4;
        float acc[4][4];
#pragma unroll
        for (int i = 0; i < 4; ++i)
#pragma unroll
            for (int k = 0; k < 4; ++k) acc[i][k] = 0.f;
        for (int c0 = 0; c0 < 256; c0 += 64) {
            __syncthreads();
            for (int idx = t; idx < 4096; idx += 256) {
                int hi = idx >> 6, lo = idx & 63;
                Als[hi * 65 + lo] = anchor_f[(size_t)(m0 + hi) * 256 + c0 + lo];
                Bls[hi * 65 + lo] = G[(size_t)(c0 + hi) * G_LD + n0 + lo];
            }
            __syncthreads();
#pragma unroll 4
            for (int cl = 0; cl < 64; ++cl) {
                float av[4], bv[4];
#pragma unroll
                for (int i = 0; i < 4; ++i) av[i] = Als[(mq * 4 + i) * 65 + cl];
#pragma unroll
                for (int k = 0; k < 4; ++k) bv[k] = Bls[cl * 65 + nq * 4 + k];
#pragma unroll
                for (int i = 0; i < 4; ++i)
#pragma unroll
                    for (int k = 0; k < 4; ++k)
                        acc[i][k] = fmaf(av[i], bv[k], acc[i][k]);
            }
        }
#pragma unroll
        for (int i = 0; i < 4; ++i) {
            int m = m0 + mq * 4 + i, b = m >> 6, la = m & 63;
#pragma unroll
            for (int k = 0; k < 4; ++k) {
                int n = n0 + nq * 4 + k;
                float v = acc[i][k] + G[(size_t)256 * G_LD + n];
                if (n < 256)      qWT[((size_t)b * 256 + n) * 64 + la] = v;
                else if (n < 320) qe_ws[(size_t)m * 64 + (n - 256)] = v;
                else if (n == 320) qbk_ws[m] = v;
            }
        }
    }
    grid_sync(bar, bar + 1);

    // ============ P2: logits (all 512 blocks) ============
    {
        const int b = bid >> 6, chunk = bid & 63, n0 = chunk * 8;
        const int la = t & 63, ng = t >> 6;
        float* nf_s = lds;            // 8*256
        float* qe_s = lds + 2048;     // 64*65 [j][la]
        float* nx_s = lds + 6208;     // 8*4
        float* mf_s = lds + 6240;     // 8

        {
            const float4* src = (const float4*)(node_f + ((size_t)b * NPB + n0) * H);
            float4* dst = (float4*)nf_s;
            dst[t] = src[t];
            dst[t + 256] = src[t + 256];
        }
#pragma unroll
        for (int i = 0; i < 16; ++i) {
            int e = t + i * 256;                       // e = la_src*64 + j
            qe_s[(e & 63) * 65 + (e >> 6)] = qe_ws[(size_t)b * 4096 + e];
        }
        if (t < 8) {
            mf_s[t] = (node_mask[b * NPB + n0 + t] - 1.0f) * 1000000.0f;
            nx_s[t * 4 + 0] = node_x[3 * (b * NPB + n0 + t) + 0];
            nx_s[t * 4 + 1] = node_x[3 * (b * NPB + n0 + t) + 1];
            nx_s[t * 4 + 2] = node_x[3 * (b * NPB + n0 + t) + 2];
        }
        __syncthreads();

        const float ax0 = anchor_x[3 * (b * 64 + la) + 0];
        const float ax1 = anchor_x[3 * (b * 64 + la) + 1];
        const float ax2 = anchor_x[3 * (b * 64 + la) + 2];
        const float qbk = qbk_ws[b * 64 + la];

        float acc0 = 0.f, acc1 = 0.f;
        {
            const float* qwcol = qWT + (size_t)b * H * 64 + la;
            const float* r0 = nf_s + ng * H;
            const float* r1 = nf_s + (ng + 4) * H;
#pragma unroll 8
            for (int k = 0; k < H; ++k) {
                float w = qwcol[(size_t)k * 64];
                acc0 = fmaf(w, r0[k], acc0);
                acc1 = fmaf(w, r1[k], acc1);
            }
        }
#pragma unroll
        for (int nn = 0; nn < 2; ++nn) {
            int nl = ng + nn * 4;
            float dx = ax0 - nx_s[nl * 4 + 0] + 1e-8f;
            float dy = ax1 - nx_s[nl * 4 + 1] + 1e-8f;
            float dz = ax2 - nx_s[nl * 4 + 2] + 1e-8f;
            float d10 = sqrtf(dx * dx + dy * dy + dz * dz) * 0.1f;
            float le = 0.f;
#pragma unroll 8
            for (int j = 0; j < HE; ++j) {
                float u = (d10 - j * MU_STEP) * INV_SIG;
                le += qe_s[j * 65 + la] * __expf(-u * u);
            }
            float lg = ((nn ? acc1 : acc0) + le + qbk) * mf_s[nl];
            lgT[((size_t)b * NPB + n0 + nl) * 64 + la] = lg;
        }
    }
    grid_sync(bar, bar + 1);

    // ============ P3: softmax + winners + upd + LN1 (all 512 blocks) ========
    {
        const int a = bid, b = a >> 6, la = a & 63;
        float* w_s   = lds;           // 512
        float* snf_s = lds + 512;     // 256
        float* rj_s  = lds + 768;     // 64
        float* red   = lds + 832;     // 256
        int*   idx_s = lds_i;         // 512
        if (t == 0) lds_i[512] = 0;

        float lg0 = lgT[((size_t)b * NPB + t) * 64 + la];
        float lg1 = lgT[((size_t)b * NPB + t + 256) * 64 + la];

        float gm = block_max(fmaxf(lg0, lg1), red4s, t);  // syncs publish cnt=0
        float e0 = __expf(lg0 - gm);
        float e1 = __expf(lg1 - gm);
        w_s[t] = e0; w_s[t + 256] = e1;
        float inv = 1.0f / block_sum(e0 + e1, red4s, t);  // syncs publish w_s

        if (e0 > 0.f) { int p = atomicAdd(&lds_i[512], 1); idx_s[p] = t; }
        if (e1 > 0.f) { int p = atomicAdd(&lds_i[512], 1); idx_s[p] = t + 256; }
        __syncthreads();
        const int cnt = lds_i[512];

        {
            float s = 0.f;
            const float* base = node_f + (size_t)(b * NPB) * H + t;
            for (int i = 0; i < cnt; ++i) {
                int n = idx_s[i];
                s += w_s[n] * base[(size_t)n * H];
            }
            snf_s[t] = s;
        }
        {
            const float ax0 = anchor_x[3 * a + 0];
            const float ax1 = anchor_x[3 * a + 1];
            const float ax2 = anchor_x[3 * a + 2];
            int j = t & 63, g = t >> 6;
            float mu = j * MU_STEP;
            float r = 0.f;
            for (int i = g; i < cnt; i += 4) {
                int n = idx_s[i];
                int ngi = b * NPB + n;
                float dx = ax0 - node_x[3 * ngi + 0] + 1e-8f;
                float dy = ax1 - node_x[3 * ngi + 1] + 1e-8f;
                float dz = ax2 - node_x[3 * ngi + 2] + 1e-8f;
                float d10 = sqrtf(dx * dx + dy * dy + dz * dz) * 0.1f;
                float u = (d10 - mu) * INV_SIG;
                r += w_s[n] * __expf(-u * u);
            }
            red[t] = r;
            __syncthreads();
            if (t < 64) rj_s[t] = red[t] + red[t + 64] + red[t + 128] + red[t + 192];
            __syncthreads();
        }

        float upd;
        {
            float u = 0.f;
#pragma unroll 8
            for (int c = 0; c < H; ++c)
                u = fmaf(KT[(size_t)c * H + t], snf_s[c], u);
            float e = 0.f;
#pragma unroll 8
            for (int j = 0; j < HE; ++j)
                e = fmaf(KT[(size_t)(H + j) * H + t], rj_s[j], e);
            upd = (u + e) * inv + bkv[H + t];
        }

        float x    = anchor_f[(size_t)a * H + t] + upd;
        float mean = block_sum(x, red4s, t) * (1.0f / 256.0f);
        float xc   = x - mean;
        float var  = block_sum(xc * xc, red4s, t) * (1.0f / 256.0f);
        af1[(size_t)a * H + t] = xc * rsqrtf(var + 1e-5f) * ln1_g[t] + ln1_b[t];
    }
    grid_sync(bar, bar + 1);

    // ============ P4: m1 = relu(af1 @ W1T + b1)  (blocks 0..255) ============
    if (bid < 256) {
        const int at = bid >> 3, nt = bid & 7;
        const int a0 = at * 16, tn = t & 63, tg = t >> 6;
        const int n = nt * 64 + tn;
        {
            const float4* src = (const float4*)(af1 + (size_t)a0 * 256);
            float4* dst = (float4*)lds;
#pragma unroll
            for (int p = 0; p < 4; ++p) dst[t + p * 256] = src[t + p * 256];
        }
        __syncthreads();
        float bv = b1[n];
        float acc[4] = {bv, bv, bv, bv};
        const float* w = W1T + n;
#pragma unroll 8
        for (int k = 0; k < 256; ++k) {
            float wv = w[(size_t)k * 512];
#pragma unroll
            for (int p = 0; p < 4; ++p)
                acc[p] = fmaf(lds[(tg + 4 * p) * 256 + k], wv, acc[p]);
        }
#pragma unroll
        for (int p = 0; p < 4; ++p)
            m1[(size_t)(a0 + tg + 4 * p) * 512 + n] = fmaxf(acc[p], 0.f);
    }
    grid_sync(bar, bar + 1);

    // ============ P5: m2 = relu(m1 @ W2T + b2)  (blocks 0..255) =============
    if (bid < 256) {
        const int at = bid >> 3, nt = bid & 7;
        const int a0 = at * 16, tn = t & 63, tg = t >> 6;
        const int n = nt * 64 + tn;
        {
            const float4* src = (const float4*)(m1 + (size_t)a0 * 512);
            float4* dst = (float4*)lds;
#pragma unroll
            for (int p = 0; p < 8; ++p) dst[t + p * 256] = src[t + p * 256];
        }
        __syncthreads();
        float bv = b2[n];
        float acc[4] = {bv, bv, bv, bv};
        const float* w = W2T + n;
#pragma unroll 8
        for (int k = 0; k < 512; ++k) {
            float wv = w[(size_t)k * 512];
#pragma unroll
            for (int p = 0; p < 4; ++p)
                acc[p] = fmaf(lds[(tg + 4 * p) * 512 + k], wv, acc[p]);
        }
#pragma unroll
        for (int p = 0; p < 4; ++p)
            m2[(size_t)(a0 + tg + 4 * p) * 512 + n] = fmaxf(acc[p], 0.f);
    }
    grid_sync(bar, bar + 1);

    // ============ P6: y3 = m2 @ W3T + b3  (blocks 0..127) ===================
    if (bid < 128) {
        const int at = bid >> 2, nt = bid & 3;
        const int a0 = at * 16, tn = t & 63, tg = t >> 6;
        const int n = nt * 64 + tn;
        {
            const float4* src = (const float4*)(m2 + (size_t)a0 * 512);
            float4* dst = (float4*)lds;
#pragma unroll
            for (int p = 0; p < 8; ++p) dst[t + p * 256] = src[t + p * 256];
        }
        __syncthreads();
        float bv = b3[n];
        float acc[4] = {bv, bv, bv, bv};
        const float* w = W3T + n;
#pragma unroll 8
        for (int k = 0; k < 512; ++k) {
            float wv = w[(size_t)k * 256];
#pragma unroll
            for (int p = 0; p < 4; ++p)
                acc[p] = fmaf(lds[(tg + 4 * p) * 512 + k], wv, acc[p]);
        }
#pragma unroll
        for (int p = 0; p < 4; ++p)
            y3[(size_t)(a0 + tg + 4 * p) * 256 + n] = acc[p];
    }
    grid_sync(bar, bar + 1);

    // ============ P7: residual + LN2 -> out (all 512 blocks) ================
    {
        const int a = bid;
        float y  = y3[(size_t)a * H + t] + af1[(size_t)a * H + t];
        float mn = block_sum(y, red4s, t) * (1.0f / 256.0f);
        float yc = y - mn;
        float vr = block_sum(yc * yc, red4s, t) * (1.0f / 256.0f);
        out[(size_t)a * H + t] = yc * rsqrtf(vr + 1e-5f) * ln2_g[t] + ln2_b[t];
    }
}

// ---------------------------------------------------------------------------
extern "C" void kernel_launch(void* const* d_in, const int* in_sizes, int n_in,
                              void* d_out, int out_size, void* d_ws, size_t ws_size,
                              hipStream_t stream)
{
    const float* anchor_x  = (const float*)d_in[0];
    const float* node_x    = (const float*)d_in[1];
    const float* anchor_f  = (const float*)d_in[2];
    const float* node_f    = (const float*)d_in[3];
    const float* node_mask = (const float*)d_in[6];
    const float* Wq        = (const float*)d_in[7];
    const float* bq        = (const float*)d_in[8];
    const float* Wkv       = (const float*)d_in[9];
    const float* bkv       = (const float*)d_in[10];
    const float* ln1_g     = (const float*)d_in[11];
    const float* ln1_b     = (const float*)d_in[12];
    const float* W1        = (const float*)d_in[13];
    const float* b1        = (const float*)d_in[14];
    const float* W2        = (const float*)d_in[15];
    const float* b2        = (const float*)d_in[16];
    const float* W3        = (const float*)d_in[17];
    const float* b3        = (const float*)d_in[18];
    const float* ln2_g     = (const float*)d_in[19];
    const float* ln2_b     = (const float*)d_in[20];

    float* ws = (float*)d_ws;

    // zero the grid-barrier state (graph-capture-safe async memset)
    hipMemsetAsync((char*)d_ws + (size_t)OFF_BAR * 4, 0, 64, stream);

    mega_kernel<<<NBLK, 256, 0, stream>>>(
        anchor_x, node_x, anchor_f, node_f, node_mask,
        Wq, bq, Wkv, bkv, ln1_g, ln1_b,
        W1, b1, W2, b2, W3, b3, ln2_g, ln2_b,
        ws, (float*)d_out);
}

// Round 7
// 259.132 us; speedup vs baseline: 4.4535x; 4.4535x over previous
//
#include <hip/hip_runtime.h>

// Problem constants (fixed by reference)
#define H    256
#define HE   64
#define NPB  512         // nodes per batch
#define NA   512         // total anchors (8 batches * 64)
#define MU_STEP (20.0f / 63.0f)
#define INV_SIG 3.2f     // 1/0.3125
#define G_LD 384

// workspace float offsets
#define OFF_G    0          // 320x384
#define OFF_QWT  122880     // [b][k][la] 8*256*64
#define OFF_QE   253952     // [a][j] 512*64
#define OFF_QBK  286720     // [a] 512 (pad 1024)
#define OFF_LGT  287744     // [b][n][la] 8*512*64
#define OFF_AF1  549888     // 512*256
#define OFF_M1   680960     // 512*512
#define OFF_M2   943104     // 512*512
#define OFF_KT   1205248    // [c][vrow] 320*256
#define OFF_W1T  1287168    // 256*512
#define OFF_W2T  1418240    // 512*512
#define OFF_W3T  1680384    // 512*256

// ---------------------------------------------------------------------------
__device__ __forceinline__ float wave_sum(float v) {
#pragma unroll
    for (int o = 32; o; o >>= 1) v += __shfl_xor(v, o, 64);
    return v;
}
__device__ __forceinline__ float wave_max(float v) {
#pragma unroll
    for (int o = 32; o; o >>= 1) v = fmaxf(v, __shfl_xor(v, o, 64));
    return v;
}
__device__ __forceinline__ float block_sum(float v, float* red4, int t) {
    v = wave_sum(v);
    if ((t & 63) == 0) red4[t >> 6] = v;
    __syncthreads();
    v = red4[0] + red4[1] + red4[2] + red4[3];
    __syncthreads();
    return v;
}
__device__ __forceinline__ float block_max(float v, float* red4, int t) {
    v = wave_max(v);
    if ((t & 63) == 0) red4[t >> 6] = v;
    __syncthreads();
    v = fmaxf(fmaxf(red4[0], red4[1]), fmaxf(red4[2], red4[3]));
    __syncthreads();
    return v;
}

// ---------------------------------------------------------------------------
// K1: weights prep. blocks 0..147 transposes (W1T,W2T,W3T,KT); 148..177:
//   G = [Wq|bq]^T @ [Wkv|bkv_k]; G[j][n], row 256 = bias row.
// ---------------------------------------------------------------------------
__global__ void __launch_bounds__(256) prep_weights(
    const float* __restrict__ Wq,  const float* __restrict__ bq,
    const float* __restrict__ Wkv, const float* __restrict__ bkv,
    const float* __restrict__ W1, const float* __restrict__ W2,
    const float* __restrict__ W3,
    float* __restrict__ G, float* __restrict__ KT,
    float* __restrict__ W1T, float* __restrict__ W2T, float* __restrict__ W3T)
{
    __shared__ float lds[8192];              // 32 KB
    const int bid = blockIdx.x, t = threadIdx.x;

    if (bid < 148) {
        float (*tile)[65] = (float(*)[65])lds;
        const float* src; float* dst; int C, Rd, tr, tc;
        if (bid < 32)       { src = W1; dst = W1T; C = 256; Rd = 512; tr = bid >> 2; tc = bid & 3; }
        else if (bid < 96)  { int ti = bid - 32; src = W2; dst = W2T; C = 512; Rd = 512; tr = ti >> 3; tc = ti & 7; }
        else if (bid < 128) { int ti = bid - 96; src = W3; dst = W3T; C = 512; Rd = 256; tr = ti >> 3; tc = ti & 7; }
        else                { int ti = bid - 128; src = Wkv + 256 * 320; dst = KT; C = 320; Rd = 256; tr = ti / 5; tc = ti % 5; }
        const int lane = t & 63, rg = t >> 6;
#pragma unroll
        for (int i = 0; i < 16; ++i) {
            int r = rg * 16 + i;
            tile[r][lane] = src[(size_t)(tr * 64 + r) * C + tc * 64 + lane];
        }
        __syncthreads();
#pragma unroll
        for (int i = 0; i < 16; ++i) {
            int r = rg * 16 + i;
            dst[(size_t)(tc * 64 + r) * Rd + tr * 64 + lane] = tile[lane][r];
        }
    } else {
        float* Als = lds;            // [o][j] 64x64
        float* Bls = lds + 4096;     // [o][n] 64x64
        const int gb = bid - 148;    // 0..29  (5 j-tiles x 6 n-tiles)
        const int mt = gb / 6, nt = gb - mt * 6;
        const int m0 = mt * 64, n0 = nt * 64;
        const int nq = t & 15, mq = t >> 4;
        float acc[4][4];
#pragma unroll
        for (int i = 0; i < 4; ++i)
#pragma unroll
            for (int k = 0; k < 4; ++k) acc[i][k] = 0.f;
        for (int c0 = 0; c0 < 256; c0 += 64) {
            __syncthreads();
            for (int idx = t; idx < 4096; idx += 256) {
                int cl = idx >> 6, el = idx & 63;
                int c = c0 + cl;
                int j = m0 + el;
                Als[idx] = (j < 256) ? Wq[(size_t)c * 256 + j] : (j == 256 ? bq[c] : 0.f);
                int n = n0 + el;
                Bls[idx] = (n < 320) ? Wkv[(size_t)c * 320 + n] : (n == 320 ? bkv[c] : 0.f);
            }
            __syncthreads();
#pragma unroll 4
            for (int cl = 0; cl < 64; ++cl) {
                const float* ar = Als + cl * 64 + mq * 4;
                const float* br = Bls + cl * 64 + nq * 4;
#pragma unroll
                for (int i = 0; i < 4; ++i)
#pragma unroll
                    for (int k = 0; k < 4; ++k)
                        acc[i][k] = fmaf(ar[i], br[k], acc[i][k]);
            }
        }
#pragma unroll
        for (int i = 0; i < 4; ++i) {
            int j = m0 + mq * 4 + i;
            float* gr = G + (size_t)j * G_LD + n0 + nq * 4;
            gr[0] = acc[i][0]; gr[1] = acc[i][1];
            gr[2] = acc[i][2]; gr[3] = acc[i][3];
        }
    }
}

// ---------------------------------------------------------------------------
// K2: anchor GEMM  [qW|qe|qbk] = AF @ G + G[256,:].  48 blocks (8m x 6n).
// ---------------------------------------------------------------------------
__global__ void __launch_bounds__(256) anchor_gemm(
    const float* __restrict__ anchor_f, const float* __restrict__ G,
    float* __restrict__ qWT, float* __restrict__ qe_ws, float* __restrict__ qbk_ws)
{
    __shared__ float Als[64 * 65];
    __shared__ float Bls[64 * 65];
    const int bid = blockIdx.x, t = threadIdx.x;
    const int mt = bid / 6, nt = bid - mt * 6;
    const int m0 = mt * 64, n0 = nt * 64;
    const int nq = t & 15, mq = t >> 4;
    float acc[4][4];
#pragma unroll
    for (int i = 0; i < 4; ++i)
#pragma unroll
        for (int k = 0; k < 4; ++k) acc[i][k] = 0.f;
    for (int c0 = 0; c0 < 256; c0 += 64) {
        __syncthreads();
        for (int idx = t; idx < 4096; idx += 256) {
            int hi = idx >> 6, lo = idx & 63;
            Als[hi * 65 + lo] = anchor_f[(size_t)(m0 + hi) * 256 + c0 + lo];
            Bls[hi * 65 + lo] = G[(size_t)(c0 + hi) * G_LD + n0 + lo];
        }
        __syncthreads();
#pragma unroll 4
        for (int cl = 0; cl < 64; ++cl) {
            float av[4], bv[4];
#pragma unroll
            for (int i = 0; i < 4; ++i) av[i] = Als[(mq * 4 + i) * 65 + cl];
#pragma unroll
            for (int k = 0; k < 4; ++k) bv[k] = Bls[cl * 65 + nq * 4 + k];
#pragma unroll
            for (int i = 0; i < 4; ++i)
#pragma unroll
                for (int k = 0; k < 4; ++k)
                    acc[i][k] = fmaf(av[i], bv[k], acc[i][k]);
        }
    }
#pragma unroll
    for (int i = 0; i < 4; ++i) {
        int m = m0 + mq * 4 + i, b = m >> 6, la = m & 63;
#pragma unroll
        for (int k = 0; k < 4; ++k) {
            int n = n0 + nq * 4 + k;
            float v = acc[i][k] + G[(size_t)256 * G_LD + n];
            if (n < 256)       qWT[((size_t)b * 256 + n) * 64 + la] = v;
            else if (n < 320)  qe_ws[(size_t)m * 64 + (n - 256)] = v;
            else if (n == 320) qbk_ws[m] = v;
        }
    }
}

// ---------------------------------------------------------------------------
// K3: logits. grid 512 = (batch, 8-node chunk); 256 thr = 64 anchors x 4 grps.
// ---------------------------------------------------------------------------
__global__ void __launch_bounds__(256) logits_kernel(
    const float* __restrict__ anchor_x, const float* __restrict__ node_x,
    const float* __restrict__ node_f,   const float* __restrict__ node_mask,
    const float* __restrict__ qWT, const float* __restrict__ qe_ws,
    const float* __restrict__ qbk_ws, float* __restrict__ lgT)
{
    const int bid = blockIdx.x, b = bid >> 6, chunk = bid & 63, n0 = chunk * 8;
    const int t = threadIdx.x, la = t & 63, ng = t >> 6;

    __shared__ float nf_s[8 * H];
    __shared__ float qe_s[64 * 65];      // [j][la], padded
    __shared__ float nx_s[8][4];
    __shared__ float mf_s[8];

    {
        const float4* src = (const float4*)(node_f + ((size_t)b * NPB + n0) * H);
        float4* dst = (float4*)nf_s;
        dst[t] = src[t];
        dst[t + 256] = src[t + 256];
    }
#pragma unroll
    for (int i = 0; i < 16; ++i) {
        int e = t + i * 256;                       // e = la_src*64 + j
        qe_s[(e & 63) * 65 + (e >> 6)] = qe_ws[(size_t)b * 4096 + e];
    }
    if (t < 8) {
        mf_s[t] = (node_mask[b * NPB + n0 + t] - 1.0f) * 1000000.0f;
        nx_s[t][0] = node_x[3 * (b * NPB + n0 + t) + 0];
        nx_s[t][1] = node_x[3 * (b * NPB + n0 + t) + 1];
        nx_s[t][2] = node_x[3 * (b * NPB + n0 + t) + 2];
    }
    __syncthreads();

    const float ax0 = anchor_x[3 * (b * 64 + la) + 0];
    const float ax1 = anchor_x[3 * (b * 64 + la) + 1];
    const float ax2 = anchor_x[3 * (b * 64 + la) + 2];
    const float qbk = qbk_ws[b * 64 + la];

    float acc0 = 0.f, acc1 = 0.f;
    {
        const float* qwcol = qWT + (size_t)b * H * 64 + la;
        const float* r0 = nf_s + ng * H;
        const float* r1 = nf_s + (ng + 4) * H;
#pragma unroll 8
        for (int k = 0; k < H; ++k) {
            float w = qwcol[(size_t)k * 64];
            acc0 = fmaf(w, r0[k], acc0);
            acc1 = fmaf(w, r1[k], acc1);
        }
    }
#pragma unroll
    for (int nn = 0; nn < 2; ++nn) {
        int nl = ng + nn * 4;
        float dx = ax0 - nx_s[nl][0] + 1e-8f;
        float dy = ax1 - nx_s[nl][1] + 1e-8f;
        float dz = ax2 - nx_s[nl][2] + 1e-8f;
        float d10 = sqrtf(dx * dx + dy * dy + dz * dz) * 0.1f;
        float le = 0.f;
#pragma unroll 8
        for (int j = 0; j < HE; ++j) {
            float u = (d10 - j * MU_STEP) * INV_SIG;
            le += qe_s[j * 65 + la] * __expf(-u * u);
        }
        float lg = ((nn ? acc1 : acc0) + le + qbk) * mf_s[nl];
        lgT[((size_t)b * NPB + n0 + nl) * 64 + la] = lg;
    }
}

// ---------------------------------------------------------------------------
// K4: per-anchor softmax + winner compaction + upd (coalesced KT) + LN1.
// ---------------------------------------------------------------------------
__global__ void __launch_bounds__(256) reduce_kernel(
    const float* __restrict__ anchor_x, const float* __restrict__ node_x,
    const float* __restrict__ anchor_f, const float* __restrict__ node_f,
    const float* __restrict__ lgT, const float* __restrict__ KT,
    const float* __restrict__ bkv,
    const float* __restrict__ ln1_g, const float* __restrict__ ln1_b,
    float* __restrict__ af1_out)
{
    const int a = blockIdx.x, b = a >> 6, la = a & 63, t = threadIdx.x;
    __shared__ float w_s[NPB], snf_s[H], rj_s[HE], red[256], red4[4];
    __shared__ int idx_s[NPB];
    __shared__ int cnt_s;
    if (t == 0) cnt_s = 0;

    float lg0 = lgT[((size_t)b * NPB + t) * 64 + la];
    float lg1 = lgT[((size_t)b * NPB + t + 256) * 64 + la];

    float gm = block_max(fmaxf(lg0, lg1), red4, t);   // syncs publish cnt_s=0
    float e0 = __expf(lg0 - gm);
    float e1 = __expf(lg1 - gm);
    w_s[t] = e0; w_s[t + 256] = e1;
    float inv = 1.0f / block_sum(e0 + e1, red4, t);   // syncs publish w_s

    if (e0 > 0.f) { int p = atomicAdd(&cnt_s, 1); idx_s[p] = t; }
    if (e1 > 0.f) { int p = atomicAdd(&cnt_s, 1); idx_s[p] = t + 256; }
    __syncthreads();
    const int cnt = cnt_s;

    {
        float s = 0.f;
        const float* base = node_f + (size_t)(b * NPB) * H + t;
        for (int i = 0; i < cnt; ++i) {
            int n = idx_s[i];
            s += w_s[n] * base[(size_t)n * H];
        }
        snf_s[t] = s;
    }
    {
        const float ax0 = anchor_x[3 * a + 0];
        const float ax1 = anchor_x[3 * a + 1];
        const float ax2 = anchor_x[3 * a + 2];
        int j = t & 63, g = t >> 6;
        float mu = j * MU_STEP;
        float r = 0.f;
        for (int i = g; i < cnt; i += 4) {
            int n = idx_s[i];
            int ngi = b * NPB + n;
            float dx = ax0 - node_x[3 * ngi + 0] + 1e-8f;
            float dy = ax1 - node_x[3 * ngi + 1] + 1e-8f;
            float dz = ax2 - node_x[3 * ngi + 2] + 1e-8f;
            float d10 = sqrtf(dx * dx + dy * dy + dz * dz) * 0.1f;
            float u = (d10 - mu) * INV_SIG;
            r += w_s[n] * __expf(-u * u);
        }
        red[t] = r;
        __syncthreads();
        if (t < 64) rj_s[t] = red[t] + red[t + 64] + red[t + 128] + red[t + 192];
        __syncthreads();
    }

    float upd;
    {
        float u = 0.f;
#pragma unroll 8
        for (int c = 0; c < H; ++c)
            u = fmaf(KT[(size_t)c * H + t], snf_s[c], u);
        float e = 0.f;
#pragma unroll 8
        for (int j = 0; j < HE; ++j)
            e = fmaf(KT[(size_t)(H + j) * H + t], rj_s[j], e);
        upd = (u + e) * inv + bkv[H + t];
    }

    float x    = anchor_f[(size_t)a * H + t] + upd;
    float mean = block_sum(x, red4, t) * (1.0f / 256.0f);
    float xc   = x - mean;
    float var  = block_sum(xc * xc, red4, t) * (1.0f / 256.0f);
    af1_out[(size_t)a * H + t] = xc * rsqrtf(var + 1e-5f) * ln1_g[t] + ln1_b[t];
}

// ---------------------------------------------------------------------------
// K5/K6: MLP GEMM (W transposed): block = 16 anchors x 64 cols, 512 threads.
// ---------------------------------------------------------------------------
template<bool RELU>
__global__ void __launch_bounds__(512) mlp_gemm(
    const float* __restrict__ A, const float* __restrict__ WT,
    const float* __restrict__ bias, float* __restrict__ out,
    int K, int N)
{
    extern __shared__ float As[];                    // [16][K]
    const int t  = threadIdx.x;
    const int tn = t & 63, tg = t >> 6;
    const int a0 = blockIdx.x * 16;
    const int n  = blockIdx.y * 64 + tn;

    {
        const float4* src = (const float4*)(A + (size_t)a0 * K);
        float4* dst = (float4*)As;
        for (int p = t; p < 4 * K; p += 512) dst[p] = src[p];
    }
    __syncthreads();

    float acc0 = bias[n], acc1 = acc0;
    const float* w = WT + n;
    const float* r0 = As + (size_t)tg * K;
    const float* r1 = As + (size_t)(tg + 8) * K;
#pragma unroll 8
    for (int k = 0; k < K; ++k) {
        float wv = w[(size_t)k * N];
        acc0 = fmaf(r0[k], wv, acc0);
        acc1 = fmaf(r1[k], wv, acc1);
    }
    if (RELU) { acc0 = fmaxf(acc0, 0.f); acc1 = fmaxf(acc1, 0.f); }
    out[(size_t)(a0 + tg) * N + n]     = acc0;
    out[(size_t)(a0 + tg + 8) * N + n] = acc1;
}

// ---------------------------------------------------------------------------
// K7: y3 = m2 @ W3T + b3, + residual(af1) + LN2 -> out.
// 128 blocks x 512 thr; block = 4 anchors x 256 cols; thread: c=t&255,
// anchors a0+(t>>8) and a0+2+(t>>8). LN per anchor over its 256 threads.
// ---------------------------------------------------------------------------
__global__ void __launch_bounds__(512) mlp3_ln2(
    const float* __restrict__ m2, const float* __restrict__ W3T,
    const float* __restrict__ b3, const float* __restrict__ af1,
    const float* __restrict__ g2, const float* __restrict__ bb2,
    float* __restrict__ out)
{
    __shared__ float As[4 * 512];                    // 8 KB
    __shared__ float red8[16];
    const int t = threadIdx.x, c = t & 255, half = t >> 8, w = t >> 6;
    const int lane = t & 63;
    const int a0 = blockIdx.x * 4;

    {
        const float4* src = (const float4*)(m2 + (size_t)a0 * 512);
        ((float4*)As)[t] = src[t];
    }
    __syncthreads();

    float acc0 = b3[c], acc1 = acc0;
    const float* wt = W3T + c;
    const float* r0 = As + (size_t)half * 512;
    const float* r1 = As + (size_t)(half + 2) * 512;
#pragma unroll 8
    for (int k = 0; k < 512; ++k) {
        float wv = wt[(size_t)k * 256];
        acc0 = fmaf(r0[k], wv, acc0);
        acc1 = fmaf(r1[k], wv, acc1);
    }

    const int aA = a0 + half, aB = a0 + 2 + half;
    float y0 = acc0 + af1[(size_t)aA * 256 + c];
    float y1 = acc1 + af1[(size_t)aB * 256 + c];

    // mean per anchor: reduce over the 256 threads sharing `half`
    float s0 = wave_sum(y0), s1 = wave_sum(y1);
    if (lane == 0) { red8[w] = s0; red8[8 + w] = s1; }
    __syncthreads();
    int base = half * 4;
    float mn0 = (red8[base] + red8[base + 1] + red8[base + 2] + red8[base + 3]) * (1.0f / 256.0f);
    float mn1 = (red8[8 + base] + red8[9 + base] + red8[10 + base] + red8[11 + base]) * (1.0f / 256.0f);
    __syncthreads();
    y0 -= mn0; y1 -= mn1;
    float v0 = wave_sum(y0 * y0), v1 = wave_sum(y1 * y1);
    if (lane == 0) { red8[w] = v0; red8[8 + w] = v1; }
    __syncthreads();
    float vr0 = (red8[base] + red8[base + 1] + red8[base + 2] + red8[base + 3]) * (1.0f / 256.0f);
    float vr1 = (red8[8 + base] + red8[9 + base] + red8[10 + base] + red8[11 + base]) * (1.0f / 256.0f);

    float gv = g2[c], bv = bb2[c];
    out[(size_t)aA * 256 + c] = y0 * rsqrtf(vr0 + 1e-5f) * gv + bv;
    out[(size_t)aB * 256 + c] = y1 * rsqrtf(vr1 + 1e-5f) * gv + bv;
}

// ---------------------------------------------------------------------------
extern "C" void kernel_launch(void* const* d_in, const int* in_sizes, int n_in,
                              void* d_out, int out_size, void* d_ws, size_t ws_size,
                              hipStream_t stream)
{
    const float* anchor_x  = (const float*)d_in[0];
    const float* node_x    = (const float*)d_in[1];
    const float* anchor_f  = (const float*)d_in[2];
    const float* node_f    = (const float*)d_in[3];
    const float* node_mask = (const float*)d_in[6];
    const float* Wq        = (const float*)d_in[7];
    const float* bq        = (const float*)d_in[8];
    const float* Wkv       = (const float*)d_in[9];
    const float* bkv       = (const float*)d_in[10];
    const float* ln1_g     = (const float*)d_in[11];
    const float* ln1_b     = (const float*)d_in[12];
    const float* W1        = (const float*)d_in[13];
    const float* b1        = (const float*)d_in[14];
    const float* W2        = (const float*)d_in[15];
    const float* b2        = (const float*)d_in[16];
    const float* W3        = (const float*)d_in[17];
    const float* b3        = (const float*)d_in[18];
    const float* ln2_g     = (const float*)d_in[19];
    const float* ln2_b     = (const float*)d_in[20];

    float* ws     = (float*)d_ws;
    float* G      = ws + OFF_G;
    float* qWT    = ws + OFF_QWT;
    float* qe_ws  = ws + OFF_QE;
    float* qbk_ws = ws + OFF_QBK;
    float* lgT    = ws + OFF_LGT;
    float* af1    = ws + OFF_AF1;
    float* m1     = ws + OFF_M1;
    float* m2     = ws + OFF_M2;
    float* KT     = ws + OFF_KT;
    float* W1T    = ws + OFF_W1T;
    float* W2T    = ws + OFF_W2T;
    float* W3T    = ws + OFF_W3T;

    prep_weights<<<178, 256, 0, stream>>>(Wq, bq, Wkv, bkv, W1, W2, W3,
                                          G, KT, W1T, W2T, W3T);

    anchor_gemm<<<48, 256, 0, stream>>>(anchor_f, G, qWT, qe_ws, qbk_ws);

    logits_kernel<<<512, 256, 0, stream>>>(anchor_x, node_x, node_f, node_mask,
                                           qWT, qe_ws, qbk_ws, lgT);

    reduce_kernel<<<NA, 256, 0, stream>>>(anchor_x, node_x, anchor_f, node_f,
                                          lgT, KT, bkv, ln1_g, ln1_b, af1);

    mlp_gemm<true><<<dim3(32, 8), 512, 16 * 256 * 4, stream>>>(af1, W1T, b1, m1, 256, 512);
    mlp_gemm<true><<<dim3(32, 8), 512, 16 * 512 * 4, stream>>>(m1,  W2T, b2, m2, 512, 512);

    mlp3_ln2<<<128, 512, 0, stream>>>(m2, W3T, b3, af1, ln2_g, ln2_b, (float*)d_out);
}

// Round 8
// 248.692 us; speedup vs baseline: 4.6405x; 1.0420x over previous
//
#include <hip/hip_runtime.h>

// Problem constants (fixed by reference)
#define H    256
#define HE   64
#define NPB  512         // nodes per batch
#define NA   512         // total anchors (8 batches * 64)
#define MU_STEP (20.0f / 63.0f)
#define INV_SIG 3.2f     // 1/0.3125
#define G_LD 384

// workspace float offsets
#define OFF_G    0          // 320x384
#define OFF_QWT  122880     // [b][k][la] 8*256*64
#define OFF_QE   253952     // [a][j] 512*64
#define OFF_QBK  286720     // [a] 512 (pad 1024)
#define OFF_LGT  287744     // [b][n][la] 8*512*64
#define OFF_AF1  549888     // 512*256
#define OFF_KT   680960     // [c][vrow] 320*256
#define OFF_W1T  762880     // 256*512
#define OFF_W2T  893952     // 512*512
#define OFF_W3T  1156096    // 512*256

// ---------------------------------------------------------------------------
__device__ __forceinline__ float wave_sum(float v) {
#pragma unroll
    for (int o = 32; o; o >>= 1) v += __shfl_xor(v, o, 64);
    return v;
}
__device__ __forceinline__ float wave_max(float v) {
#pragma unroll
    for (int o = 32; o; o >>= 1) v = fmaxf(v, __shfl_xor(v, o, 64));
    return v;
}
__device__ __forceinline__ float block_sum(float v, float* red4, int t) {
    v = wave_sum(v);
    if ((t & 63) == 0) red4[t >> 6] = v;
    __syncthreads();
    v = red4[0] + red4[1] + red4[2] + red4[3];
    __syncthreads();
    return v;
}
__device__ __forceinline__ float block_max(float v, float* red4, int t) {
    v = wave_max(v);
    if ((t & 63) == 0) red4[t >> 6] = v;
    __syncthreads();
    v = fmaxf(fmaxf(red4[0], red4[1]), fmaxf(red4[2], red4[3]));
    __syncthreads();
    return v;
}
__device__ __forceinline__ float block_sum512(float v, float* red8, int t) {
    v = wave_sum(v);
    if ((t & 63) == 0) red8[t >> 6] = v;
    __syncthreads();
    v = red8[0] + red8[1] + red8[2] + red8[3]
      + red8[4] + red8[5] + red8[6] + red8[7];
    __syncthreads();
    return v;
}

// ---------------------------------------------------------------------------
// K1: G = [Wq|bq]^T @ [Wkv|bkv_k].  30 blocks (5 j-tiles x 6 n-tiles).
//   G[j][n], j in [0,320) (row 256 = bias row), n: 0..255 qW, 256..319 qe, 320 qbk.
// ---------------------------------------------------------------------------
__global__ void __launch_bounds__(256) g_kernel(
    const float* __restrict__ Wq,  const float* __restrict__ bq,
    const float* __restrict__ Wkv, const float* __restrict__ bkv,
    float* __restrict__ G)
{
    __shared__ float Als[4096];      // [o][j] 64x64
    __shared__ float Bls[4096];      // [o][n] 64x64
    const int gb = blockIdx.x, t = threadIdx.x;
    const int mt = gb / 6, nt = gb - mt * 6;
    const int m0 = mt * 64, n0 = nt * 64;
    const int nq = t & 15, mq = t >> 4;
    float acc[4][4];
#pragma unroll
    for (int i = 0; i < 4; ++i)
#pragma unroll
        for (int k = 0; k < 4; ++k) acc[i][k] = 0.f;
    for (int c0 = 0; c0 < 256; c0 += 64) {
        __syncthreads();
        for (int idx = t; idx < 4096; idx += 256) {
            int cl = idx >> 6, el = idx & 63;
            int c = c0 + cl;
            int j = m0 + el;
            Als[idx] = (j < 256) ? Wq[(size_t)c * 256 + j] : (j == 256 ? bq[c] : 0.f);
            int n = n0 + el;
            Bls[idx] = (n < 320) ? Wkv[(size_t)c * 320 + n] : (n == 320 ? bkv[c] : 0.f);
        }
        __syncthreads();
#pragma unroll 4
        for (int cl = 0; cl < 64; ++cl) {
            const float* ar = Als + cl * 64 + mq * 4;
            const float* br = Bls + cl * 64 + nq * 4;
#pragma unroll
            for (int i = 0; i < 4; ++i)
#pragma unroll
                for (int k = 0; k < 4; ++k)
                    acc[i][k] = fmaf(ar[i], br[k], acc[i][k]);
        }
    }
#pragma unroll
    for (int i = 0; i < 4; ++i) {
        int j = m0 + mq * 4 + i;
        float* gr = G + (size_t)j * G_LD + n0 + nq * 4;
        gr[0] = acc[i][0]; gr[1] = acc[i][1];
        gr[2] = acc[i][2]; gr[3] = acc[i][3];
    }
}

// ---------------------------------------------------------------------------
// K2: blocks 0..47 anchor GEMM [qW|qe|qbk] = AF @ G + G[256,:];
//     blocks 48..195 weight transposes (W1T, W2T, W3T, KT) — independent.
// ---------------------------------------------------------------------------
__global__ void __launch_bounds__(256) anchor_wt(
    const float* __restrict__ anchor_f, const float* __restrict__ G,
    const float* __restrict__ Wkv,
    const float* __restrict__ W1, const float* __restrict__ W2,
    const float* __restrict__ W3,
    float* __restrict__ qWT, float* __restrict__ qe_ws, float* __restrict__ qbk_ws,
    float* __restrict__ KT,
    float* __restrict__ W1T, float* __restrict__ W2T, float* __restrict__ W3T)
{
    __shared__ float lds[8320];          // anchor: Als 64x65 + Bls 64x65
    const int bid = blockIdx.x, t = threadIdx.x;

    if (bid < 48) {
        float* Als = lds;
        float* Bls = lds + 4160;
        const int mt = bid / 6, nt = bid - mt * 6;
        const int m0 = mt * 64, n0 = nt * 64;
        const int nq = t & 15, mq = t >> 4;
        float acc[4][4];
#pragma unroll
        for (int i = 0; i < 4; ++i)
#pragma unroll
            for (int k = 0; k < 4; ++k) acc[i][k] = 0.f;
        for (int c0 = 0; c0 < 256; c0 += 64) {
            __syncthreads();
            for (int idx = t; idx < 4096; idx += 256) {
                int hi = idx >> 6, lo = idx & 63;
                Als[hi * 65 + lo] = anchor_f[(size_t)(m0 + hi) * 256 + c0 + lo];
                Bls[hi * 65 + lo] = G[(size_t)(c0 + hi) * G_LD + n0 + lo];
            }
            __syncthreads();
#pragma unroll 4
            for (int cl = 0; cl < 64; ++cl) {
                float av[4], bv[4];
#pragma unroll
                for (int i = 0; i < 4; ++i) av[i] = Als[(mq * 4 + i) * 65 + cl];
#pragma unroll
                for (int k = 0; k < 4; ++k) bv[k] = Bls[cl * 65 + nq * 4 + k];
#pragma unroll
                for (int i = 0; i < 4; ++i)
#pragma unroll
                    for (int k = 0; k < 4; ++k)
                        acc[i][k] = fmaf(av[i], bv[k], acc[i][k]);
            }
        }
#pragma unroll
        for (int i = 0; i < 4; ++i) {
            int m = m0 + mq * 4 + i, b = m >> 6, la = m & 63;
#pragma unroll
            for (int k = 0; k < 4; ++k) {
                int n = n0 + nq * 4 + k;
                float v = acc[i][k] + G[(size_t)256 * G_LD + n];
                if (n < 256)       qWT[((size_t)b * 256 + n) * 64 + la] = v;
                else if (n < 320)  qe_ws[(size_t)m * 64 + (n - 256)] = v;
                else if (n == 320) qbk_ws[m] = v;
            }
        }
    } else {
        float (*tile)[65] = (float(*)[65])lds;
        const int ti0 = bid - 48;
        const float* src; float* dst; int C, Rd, tr, tc;
        if (ti0 < 32)       { src = W1; dst = W1T; C = 256; Rd = 512; tr = ti0 >> 2; tc = ti0 & 3; }
        else if (ti0 < 96)  { int ti = ti0 - 32; src = W2; dst = W2T; C = 512; Rd = 512; tr = ti >> 3; tc = ti & 7; }
        else if (ti0 < 128) { int ti = ti0 - 96; src = W3; dst = W3T; C = 512; Rd = 256; tr = ti >> 3; tc = ti & 7; }
        else                { int ti = ti0 - 128; src = Wkv + 256 * 320; dst = KT; C = 320; Rd = 256; tr = ti / 5; tc = ti % 5; }
        const int lane = t & 63, rg = t >> 6;
#pragma unroll
        for (int i = 0; i < 16; ++i) {
            int r = rg * 16 + i;
            tile[r][lane] = src[(size_t)(tr * 64 + r) * C + tc * 64 + lane];
        }
        __syncthreads();
#pragma unroll
        for (int i = 0; i < 16; ++i) {
            int r = rg * 16 + i;
            dst[(size_t)(tc * 64 + r) * Rd + tr * 64 + lane] = tile[lane][r];
        }
    }
}

// ---------------------------------------------------------------------------
// K3: logits. grid 512 = (batch, 8-node chunk); 256 thr = 64 anchors x 4 grps.
// ---------------------------------------------------------------------------
__global__ void __launch_bounds__(256) logits_kernel(
    const float* __restrict__ anchor_x, const float* __restrict__ node_x,
    const float* __restrict__ node_f,   const float* __restrict__ node_mask,
    const float* __restrict__ qWT, const float* __restrict__ qe_ws,
    const float* __restrict__ qbk_ws, float* __restrict__ lgT)
{
    const int bid = blockIdx.x, b = bid >> 6, chunk = bid & 63, n0 = chunk * 8;
    const int t = threadIdx.x, la = t & 63, ng = t >> 6;

    __shared__ float nf_s[8 * H];
    __shared__ float qe_s[64 * 65];      // [j][la], padded
    __shared__ float nx_s[8][4];
    __shared__ float mf_s[8];

    {
        const float4* src = (const float4*)(node_f + ((size_t)b * NPB + n0) * H);
        float4* dst = (float4*)nf_s;
        dst[t] = src[t];
        dst[t + 256] = src[t + 256];
    }
#pragma unroll
    for (int i = 0; i < 16; ++i) {
        int e = t + i * 256;                       // e = la_src*64 + j
        qe_s[(e & 63) * 65 + (e >> 6)] = qe_ws[(size_t)b * 4096 + e];
    }
    if (t < 8) {
        mf_s[t] = (node_mask[b * NPB + n0 + t] - 1.0f) * 1000000.0f;
        nx_s[t][0] = node_x[3 * (b * NPB + n0 + t) + 0];
        nx_s[t][1] = node_x[3 * (b * NPB + n0 + t) + 1];
        nx_s[t][2] = node_x[3 * (b * NPB + n0 + t) + 2];
    }
    __syncthreads();

    const float ax0 = anchor_x[3 * (b * 64 + la) + 0];
    const float ax1 = anchor_x[3 * (b * 64 + la) + 1];
    const float ax2 = anchor_x[3 * (b * 64 + la) + 2];
    const float qbk = qbk_ws[b * 64 + la];

    float acc0 = 0.f, acc1 = 0.f;
    {
        const float* qwcol = qWT + (size_t)b * H * 64 + la;
        const float* r0 = nf_s + ng * H;
        const float* r1 = nf_s + (ng + 4) * H;
#pragma unroll 8
        for (int k = 0; k < H; ++k) {
            float w = qwcol[(size_t)k * 64];
            acc0 = fmaf(w, r0[k], acc0);
            acc1 = fmaf(w, r1[k], acc1);
        }
    }
#pragma unroll
    for (int nn = 0; nn < 2; ++nn) {
        int nl = ng + nn * 4;
        float dx = ax0 - nx_s[nl][0] + 1e-8f;
        float dy = ax1 - nx_s[nl][1] + 1e-8f;
        float dz = ax2 - nx_s[nl][2] + 1e-8f;
        float d10 = sqrtf(dx * dx + dy * dy + dz * dz) * 0.1f;
        float le = 0.f;
#pragma unroll 8
        for (int j = 0; j < HE; ++j) {
            float u = (d10 - j * MU_STEP) * INV_SIG;
            le += qe_s[j * 65 + la] * __expf(-u * u);
        }
        float lg = ((nn ? acc1 : acc0) + le + qbk) * mf_s[nl];
        lgT[((size_t)b * NPB + n0 + nl) * 64 + la] = lg;
    }
}

// ---------------------------------------------------------------------------
// K4: per-anchor softmax + winner compaction + upd (coalesced KT) + LN1.
// ---------------------------------------------------------------------------
__global__ void __launch_bounds__(256) reduce_kernel(
    const float* __restrict__ anchor_x, const float* __restrict__ node_x,
    const float* __restrict__ anchor_f, const float* __restrict__ node_f,
    const float* __restrict__ lgT, const float* __restrict__ KT,
    const float* __restrict__ bkv,
    const float* __restrict__ ln1_g, const float* __restrict__ ln1_b,
    float* __restrict__ af1_out)
{
    const int a = blockIdx.x, b = a >> 6, la = a & 63, t = threadIdx.x;
    __shared__ float w_s[NPB], snf_s[H], rj_s[HE], red[256], red4[4];
    __shared__ int idx_s[NPB];
    __shared__ int cnt_s;
    if (t == 0) cnt_s = 0;

    float lg0 = lgT[((size_t)b * NPB + t) * 64 + la];
    float lg1 = lgT[((size_t)b * NPB + t + 256) * 64 + la];

    float gm = block_max(fmaxf(lg0, lg1), red4, t);   // syncs publish cnt_s=0
    float e0 = __expf(lg0 - gm);
    float e1 = __expf(lg1 - gm);
    w_s[t] = e0; w_s[t + 256] = e1;
    float inv = 1.0f / block_sum(e0 + e1, red4, t);   // syncs publish w_s

    if (e0 > 0.f) { int p = atomicAdd(&cnt_s, 1); idx_s[p] = t; }
    if (e1 > 0.f) { int p = atomicAdd(&cnt_s, 1); idx_s[p] = t + 256; }
    __syncthreads();
    const int cnt = cnt_s;

    {
        float s = 0.f;
        const float* base = node_f + (size_t)(b * NPB) * H + t;
        for (int i = 0; i < cnt; ++i) {
            int n = idx_s[i];
            s += w_s[n] * base[(size_t)n * H];
        }
        snf_s[t] = s;
    }
    {
        const float ax0 = anchor_x[3 * a + 0];
        const float ax1 = anchor_x[3 * a + 1];
        const float ax2 = anchor_x[3 * a + 2];
        int j = t & 63, g = t >> 6;
        float mu = j * MU_STEP;
        float r = 0.f;
        for (int i = g; i < cnt; i += 4) {
            int n = idx_s[i];
            int ngi = b * NPB + n;
            float dx = ax0 - node_x[3 * ngi + 0] + 1e-8f;
            float dy = ax1 - node_x[3 * ngi + 1] + 1e-8f;
            float dz = ax2 - node_x[3 * ngi + 2] + 1e-8f;
            float d10 = sqrtf(dx * dx + dy * dy + dz * dz) * 0.1f;
            float u = (d10 - mu) * INV_SIG;
            r += w_s[n] * __expf(-u * u);
        }
        red[t] = r;
        __syncthreads();
        if (t < 64) rj_s[t] = red[t] + red[t + 64] + red[t + 128] + red[t + 192];
        __syncthreads();
    }

    float upd;
    {
        float u = 0.f;
#pragma unroll 8
        for (int c = 0; c < H; ++c)
            u = fmaf(KT[(size_t)c * H + t], snf_s[c], u);
        float e = 0.f;
#pragma unroll 8
        for (int j = 0; j < HE; ++j)
            e = fmaf(KT[(size_t)(H + j) * H + t], rj_s[j], e);
        upd = (u + e) * inv + bkv[H + t];
    }

    float x    = anchor_f[(size_t)a * H + t] + upd;
    float mean = block_sum(x, red4, t) * (1.0f / 256.0f);
    float xc   = x - mean;
    float var  = block_sum(xc * xc, red4, t) * (1.0f / 256.0f);
    af1_out[(size_t)a * H + t] = xc * rsqrtf(var + 1e-5f) * ln1_g[t] + ln1_b[t];
}

// ---------------------------------------------------------------------------
// K5: fused MLP (3 layers) + residual + LN2.  128 blocks x 512 threads,
// 4 anchors per block; m1/m2 staged in LDS; WT read coalesced from L2
// (weights 2 MB x 128 blocks = 256 MB L2 traffic ~7us at 34.5 TB/s).
// ---------------------------------------------------------------------------
__global__ void __launch_bounds__(512) mlp_fused(
    const float* __restrict__ af1,
    const float* __restrict__ W1T, const float* __restrict__ b1,
    const float* __restrict__ W2T, const float* __restrict__ b2,
    const float* __restrict__ W3T, const float* __restrict__ b3,
    const float* __restrict__ g2,  const float* __restrict__ bb2,
    float* __restrict__ out)
{
    __shared__ float af_s[4 * 256];
    __shared__ float m1_s[4 * 512];
    __shared__ float m2_s[4 * 512];
    __shared__ float red8[8];
    const int t = threadIdx.x;
    const int a0 = blockIdx.x * 4;

    if (t < 256) ((float4*)af_s)[t] = ((const float4*)(af1 + (size_t)a0 * 256))[t];
    __syncthreads();

    // ---- L1: m1[p][t] = relu(b1[t] + sum_k af[p][k]*W1T[k][t]) ----
    {
        float bv = b1[t];
        float acc[4] = {bv, bv, bv, bv};
        const float* w = W1T + t;
#pragma unroll 2
        for (int k = 0; k < 256; k += 4) {
            float wv0 = w[(size_t)(k + 0) * 512];
            float wv1 = w[(size_t)(k + 1) * 512];
            float wv2 = w[(size_t)(k + 2) * 512];
            float wv3 = w[(size_t)(k + 3) * 512];
#pragma unroll
            for (int p = 0; p < 4; ++p) {
                float4 av = *(const float4*)&af_s[p * 256 + k];
                acc[p] = fmaf(av.x, wv0, acc[p]);
                acc[p] = fmaf(av.y, wv1, acc[p]);
                acc[p] = fmaf(av.z, wv2, acc[p]);
                acc[p] = fmaf(av.w, wv3, acc[p]);
            }
        }
#pragma unroll
        for (int p = 0; p < 4; ++p) m1_s[p * 512 + t] = fmaxf(acc[p], 0.f);
    }
    __syncthreads();

    // ---- L2: m2[p][t] = relu(b2[t] + sum_k m1[p][k]*W2T[k][t]) ----
    {
        float bv = b2[t];
        float acc[4] = {bv, bv, bv, bv};
        const float* w = W2T + t;
#pragma unroll 2
        for (int k = 0; k < 512; k += 4) {
            float wv0 = w[(size_t)(k + 0) * 512];
            float wv1 = w[(size_t)(k + 1) * 512];
            float wv2 = w[(size_t)(k + 2) * 512];
            float wv3 = w[(size_t)(k + 3) * 512];
#pragma unroll
            for (int p = 0; p < 4; ++p) {
                float4 av = *(const float4*)&m1_s[p * 512 + k];
                acc[p] = fmaf(av.x, wv0, acc[p]);
                acc[p] = fmaf(av.y, wv1, acc[p]);
                acc[p] = fmaf(av.z, wv2, acc[p]);
                acc[p] = fmaf(av.w, wv3, acc[p]);
            }
        }
#pragma unroll
        for (int p = 0; p < 4; ++p) m2_s[p * 512 + t] = fmaxf(acc[p], 0.f);
    }
    __syncthreads();

    // ---- L3 (k-split in 2 halves): y[p][th] = b3 + sum_k m2[p][k]*W3T[k][th] ----
    const int th = t & 255, kh = t >> 8;
    {
        float pacc[4];
        float bv = (kh == 0) ? b3[th] : 0.f;
#pragma unroll
        for (int p = 0; p < 4; ++p) pacc[p] = bv;
        const float* w = W3T + th;
        const int kb = kh * 256;
#pragma unroll 2
        for (int k = 0; k < 256; k += 4) {
            float wv0 = w[(size_t)(kb + k + 0) * 256];
            float wv1 = w[(size_t)(kb + k + 1) * 256];
            float wv2 = w[(size_t)(kb + k + 2) * 256];
            float wv3 = w[(size_t)(kb + k + 3) * 256];
#pragma unroll
            for (int p = 0; p < 4; ++p) {
                float4 av = *(const float4*)&m2_s[p * 512 + kb + k];
                pacc[p] = fmaf(av.x, wv0, pacc[p]);
                pacc[p] = fmaf(av.y, wv1, pacc[p]);
                pacc[p] = fmaf(av.z, wv2, pacc[p]);
                pacc[p] = fmaf(av.w, wv3, pacc[p]);
            }
        }
        // combine halves through m1_s (dead)
#pragma unroll
        for (int p = 0; p < 4; ++p) m1_s[p * 512 + t] = pacc[p];
    }
    __syncthreads();

    float y[4];
    if (kh == 0) {
#pragma unroll
        for (int p = 0; p < 4; ++p)
            y[p] = m1_s[p * 512 + th] + m1_s[p * 512 + th + 256] + af_s[p * 256 + th];
    }
    float gv = 0.f, bv2 = 0.f;
    if (kh == 0) { gv = g2[th]; bv2 = bb2[th]; }

#pragma unroll
    for (int p = 0; p < 4; ++p) {
        float s  = block_sum512((kh == 0) ? y[p] : 0.f, red8, t);
        float mn = s * (1.0f / 256.0f);
        float yc = (kh == 0) ? (y[p] - mn) : 0.f;
        float vr = block_sum512(yc * yc, red8, t) * (1.0f / 256.0f);
        if (kh == 0)
            out[(size_t)(a0 + p) * 256 + th] = yc * rsqrtf(vr + 1e-5f) * gv + bv2;
    }
}

// ---------------------------------------------------------------------------
extern "C" void kernel_launch(void* const* d_in, const int* in_sizes, int n_in,
                              void* d_out, int out_size, void* d_ws, size_t ws_size,
                              hipStream_t stream)
{
    const float* anchor_x  = (const float*)d_in[0];
    const float* node_x    = (const float*)d_in[1];
    const float* anchor_f  = (const float*)d_in[2];
    const float* node_f    = (const float*)d_in[3];
    const float* node_mask = (const float*)d_in[6];
    const float* Wq        = (const float*)d_in[7];
    const float* bq        = (const float*)d_in[8];
    const float* Wkv       = (const float*)d_in[9];
    const float* bkv       = (const float*)d_in[10];
    const float* ln1_g     = (const float*)d_in[11];
    const float* ln1_b     = (const float*)d_in[12];
    const float* W1        = (const float*)d_in[13];
    const float* b1        = (const float*)d_in[14];
    const float* W2        = (const float*)d_in[15];
    const float* b2        = (const float*)d_in[16];
    const float* W3        = (const float*)d_in[17];
    const float* b3        = (const float*)d_in[18];
    const float* ln2_g     = (const float*)d_in[19];
    const float* ln2_b     = (const float*)d_in[20];

    float* ws     = (float*)d_ws;
    float* G      = ws + OFF_G;
    float* qWT    = ws + OFF_QWT;
    float* qe_ws  = ws + OFF_QE;
    float* qbk_ws = ws + OFF_QBK;
    float* lgT    = ws + OFF_LGT;
    float* af1    = ws + OFF_AF1;
    float* KT     = ws + OFF_KT;
    float* W1T    = ws + OFF_W1T;
    float* W2T    = ws + OFF_W2T;
    float* W3T    = ws + OFF_W3T;

    g_kernel<<<30, 256, 0, stream>>>(Wq, bq, Wkv, bkv, G);

    anchor_wt<<<196, 256, 0, stream>>>(anchor_f, G, Wkv, W1, W2, W3,
                                       qWT, qe_ws, qbk_ws, KT, W1T, W2T, W3T);

    logits_kernel<<<512, 256, 0, stream>>>(anchor_x, node_x, node_f, node_mask,
                                           qWT, qe_ws, qbk_ws, lgT);

    reduce_kernel<<<NA, 256, 0, stream>>>(anchor_x, node_x, anchor_f, node_f,
                                          lgT, KT, bkv, ln1_g, ln1_b, af1);

    mlp_fused<<<128, 512, 0, stream>>>(af1, W1T, b1, W2T, b2, W3T, b3,
                                       ln2_g, ln2_b, (float*)d_out);
}

// Round 9
// 228.180 us; speedup vs baseline: 5.0577x; 1.0899x over previous
//
#include <hip/hip_runtime.h>

// Problem constants (fixed by reference)
#define H    256
#define HE   64
#define NPB  512         // nodes per batch
#define NA   512         // total anchors (8 batches * 64)
#define MU_STEP (20.0f / 63.0f)
#define INV_SIG 3.2f     // 1/0.3125
#define G_LD 384

// workspace float offsets
#define OFF_G    0          // 320x384
#define OFF_KT   122880     // [c][vrow] 320*256
#define OFF_W1T  204800     // 256*512
#define OFF_W2T  335872     // 512*512
#define OFF_W3T  598016     // 512*256
#define OFF_AF1  729088     // 512*256

// ---------------------------------------------------------------------------
__device__ __forceinline__ float wave_sum(float v) {
#pragma unroll
    for (int o = 32; o; o >>= 1) v += __shfl_xor(v, o, 64);
    return v;
}
__device__ __forceinline__ float wave_max(float v) {
#pragma unroll
    for (int o = 32; o; o >>= 1) v = fmaxf(v, __shfl_xor(v, o, 64));
    return v;
}
__device__ __forceinline__ float block_sum(float v, float* red4, int t) {
    v = wave_sum(v);
    if ((t & 63) == 0) red4[t >> 6] = v;
    __syncthreads();
    v = red4[0] + red4[1] + red4[2] + red4[3];
    __syncthreads();
    return v;
}
__device__ __forceinline__ float block_max(float v, float* red4, int t) {
    v = wave_max(v);
    if ((t & 63) == 0) red4[t >> 6] = v;
    __syncthreads();
    v = fmaxf(fmaxf(red4[0], red4[1]), fmaxf(red4[2], red4[3]));
    __syncthreads();
    return v;
}
__device__ __forceinline__ float block_sum512(float v, float* red8, int t) {
    v = wave_sum(v);
    if ((t & 63) == 0) red8[t >> 6] = v;
    __syncthreads();
    v = red8[0] + red8[1] + red8[2] + red8[3]
      + red8[4] + red8[5] + red8[6] + red8[7];
    __syncthreads();
    return v;
}

// ---------------------------------------------------------------------------
// K1: weights prep (first dispatch — absorbs the fixed ~50us first-slot cost).
//  blocks 0..147: transposes (W1T, W2T, W3T, KT); 148..177: G GEMM.
//  G[j][n] = sum_c [Wq|bq][c][j] * [Wkv|bkv_k][c][n]; row 256 = bias row.
// ---------------------------------------------------------------------------
__global__ void __launch_bounds__(256) prep_weights(
    const float* __restrict__ Wq,  const float* __restrict__ bq,
    const float* __restrict__ Wkv, const float* __restrict__ bkv,
    const float* __restrict__ W1, const float* __restrict__ W2,
    const float* __restrict__ W3,
    float* __restrict__ G, float* __restrict__ KT,
    float* __restrict__ W1T, float* __restrict__ W2T, float* __restrict__ W3T)
{
    __shared__ float lds[8192];              // 32 KB
    const int bid = blockIdx.x, t = threadIdx.x;

    if (bid < 148) {
        float (*tile)[65] = (float(*)[65])lds;
        const float* src; float* dst; int C, Rd, tr, tc;
        if (bid < 32)       { src = W1; dst = W1T; C = 256; Rd = 512; tr = bid >> 2; tc = bid & 3; }
        else if (bid < 96)  { int ti = bid - 32; src = W2; dst = W2T; C = 512; Rd = 512; tr = ti >> 3; tc = ti & 7; }
        else if (bid < 128) { int ti = bid - 96; src = W3; dst = W3T; C = 512; Rd = 256; tr = ti >> 3; tc = ti & 7; }
        else                { int ti = bid - 128; src = Wkv + 256 * 320; dst = KT; C = 320; Rd = 256; tr = ti / 5; tc = ti % 5; }
        const int lane = t & 63, rg = t >> 6;
#pragma unroll
        for (int i = 0; i < 16; ++i) {
            int r = rg * 16 + i;
            tile[r][lane] = src[(size_t)(tr * 64 + r) * C + tc * 64 + lane];
        }
        __syncthreads();
#pragma unroll
        for (int i = 0; i < 16; ++i) {
            int r = rg * 16 + i;
            dst[(size_t)(tc * 64 + r) * Rd + tr * 64 + lane] = tile[lane][r];
        }
    } else {
        float* Als = lds;            // [c][j] 64x64
        float* Bls = lds + 4096;     // [c][n] 64x64
        const int gb = bid - 148;    // 0..29  (5 j-tiles x 6 n-tiles)
        const int mt = gb / 6, nt = gb - mt * 6;
        const int m0 = mt * 64, n0 = nt * 64;
        const int nq = t & 15, mq = t >> 4;
        float acc[4][4];
#pragma unroll
        for (int i = 0; i < 4; ++i)
#pragma unroll
            for (int k = 0; k < 4; ++k) acc[i][k] = 0.f;
        for (int c0 = 0; c0 < 256; c0 += 64) {
            __syncthreads();
            for (int idx = t; idx < 4096; idx += 256) {
                int cl = idx >> 6, el = idx & 63;
                int c = c0 + cl;
                int j = m0 + el;
                Als[idx] = (j < 256) ? Wq[(size_t)c * 256 + j] : (j == 256 ? bq[c] : 0.f);
                int n = n0 + el;
                Bls[idx] = (n < 320) ? Wkv[(size_t)c * 320 + n] : (n == 320 ? bkv[c] : 0.f);
            }
            __syncthreads();
#pragma unroll 4
            for (int cl = 0; cl < 64; ++cl) {
                const float* ar = Als + cl * 64 + mq * 4;
                const float* br = Bls + cl * 64 + nq * 4;
#pragma unroll
                for (int i = 0; i < 4; ++i)
#pragma unroll
                    for (int k = 0; k < 4; ++k)
                        acc[i][k] = fmaf(ar[i], br[k], acc[i][k]);
            }
        }
#pragma unroll
        for (int i = 0; i < 4; ++i) {
            int j = m0 + mq * 4 + i;
            float* gr = G + (size_t)j * G_LD + n0 + nq * 4;
            gr[0] = acc[i][0]; gr[1] = acc[i][1];
            gr[2] = acc[i][2]; gr[3] = acc[i][3];
        }
    }
}

// ---------------------------------------------------------------------------
// K2: fully fused attention per anchor. 512 blocks x 256 threads.
//  Phase B: [qW|qe|qbk] = af @ G + G[256,:]   (8-batched coalesced G loads)
//  Phase C: logits over 32 double-buffered 16-node LDS tiles
//           (split-k: thread = (node n16 = t>>4, k-chunk kc = t&15))
//  Phase D: softmax + winner compaction + snf/rj + upd (KT coalesced) + LN1
// ---------------------------------------------------------------------------
__global__ void __launch_bounds__(256) attn_fused(
    const float* __restrict__ anchor_x, const float* __restrict__ node_x,
    const float* __restrict__ anchor_f, const float* __restrict__ node_f,
    const float* __restrict__ node_mask,
    const float* __restrict__ G, const float* __restrict__ KT,
    const float* __restrict__ bkv,
    const float* __restrict__ ln1_g, const float* __restrict__ ln1_b,
    float* __restrict__ af1_out)
{
    const int a = blockIdx.x, b = a >> 6, t = threadIdx.x;

    __shared__ float af_s[256], qW_s[256], qe_s[65];   // qe_s[64] = qbk
    __shared__ float nf_s[2][16 * 256];                // 32 KB double buffer
    __shared__ float d10_s[NPB], mf_s[NPB], lg_s[NPB], w_s[NPB];
    __shared__ float snf_s[256], rj_s[64], red[256], red4[4];
    __shared__ int   idx_s[NPB];
    __shared__ int   cnt_s;

    af_s[t] = anchor_f[(size_t)a * 256 + t];
    if (t == 0) cnt_s = 0;

    // d10 + mask factor for nodes t, t+256
    {
        const float ax0 = anchor_x[3 * a + 0];
        const float ax1 = anchor_x[3 * a + 1];
        const float ax2 = anchor_x[3 * a + 2];
#pragma unroll
        for (int nn = 0; nn < 2; ++nn) {
            int n = t + nn * 256, ng = b * NPB + n;
            float dx = ax0 - node_x[3 * ng + 0] + 1e-8f;
            float dy = ax1 - node_x[3 * ng + 1] + 1e-8f;
            float dz = ax2 - node_x[3 * ng + 2] + 1e-8f;
            d10_s[n] = sqrtf(dx * dx + dy * dy + dz * dz) * 0.1f;
            mf_s[n]  = (node_mask[ng] - 1.0f) * 1000000.0f;
        }
    }
    __syncthreads();   // af_s ready

    // ---- Phase B: qW[t], qe[t<64], qbk(t==64) from G (batched loads) ----
    {
        float acc0 = G[(size_t)256 * G_LD + t];
        const bool hb = (t <= 64);
        float acc1 = hb ? G[(size_t)256 * G_LD + 256 + t] : 0.f;
        for (int c = 0; c < 256; c += 8) {
            float a8[8], b8[8];
#pragma unroll
            for (int u = 0; u < 8; ++u) a8[u] = G[(size_t)(c + u) * G_LD + t];
            if (hb) {
#pragma unroll
                for (int u = 0; u < 8; ++u) b8[u] = G[(size_t)(c + u) * G_LD + 256 + t];
            }
#pragma unroll
            for (int u = 0; u < 8; ++u) {
                float av = af_s[c + u];
                acc0 = fmaf(av, a8[u], acc0);
                if (hb) acc1 = fmaf(av, b8[u], acc1);
            }
        }
        qW_s[t] = acc0;
        if (t <= 64) qe_s[t] = acc1;
    }

    // preload tile 0 (16 nodes x 256 floats = 1024 float4)
    const float4* src0 = (const float4*)(node_f + (size_t)(b * NPB) * 256);
    float4 rA = src0[t], rB = src0[t + 256], rC = src0[t + 512], rD = src0[t + 768];

    __syncthreads();   // qW_s / qe_s ready

    const float qbk = qe_s[64];
    const int n16 = t >> 4, kc = t & 15;

    // ---- Phase C: logits, double-buffered 16-node tiles ----
    for (int tile = 0; tile < 32; ++tile) {
        float4* dst = (float4*)(nf_s[tile & 1]);
        dst[t] = rA; dst[t + 256] = rB; dst[t + 512] = rC; dst[t + 768] = rD;
        if (tile < 31) {
            const float4* s2 = (const float4*)(node_f + (size_t)(b * NPB + (tile + 1) * 16) * 256);
            rA = s2[t]; rB = s2[t + 256]; rC = s2[t + 512]; rD = s2[t + 768];
        }
        __syncthreads();

        const float* nf = nf_s[tile & 1] + n16 * 256;
        const int n = tile * 16 + n16;
        const float d10 = d10_s[n];
        float s = 0.f;
#pragma unroll
        for (int u = 0; u < 16; ++u) {
            int k = kc + 16 * u;               // strided k: 4-way LDS aliasing only
            s = fmaf(qW_s[k], nf[k], s);
        }
#pragma unroll
        for (int u = 0; u < 4; ++u) {
            int j = kc * 4 + u;
            float uu = (d10 - j * MU_STEP) * INV_SIG;
            s = fmaf(qe_s[j], __expf(-uu * uu), s);
        }
#pragma unroll
        for (int o = 1; o < 16; o <<= 1) s += __shfl_xor(s, o, 64);
        if (kc == 0) lg_s[n] = (s + qbk) * mf_s[n];
        __syncthreads();                        // compute done before next store
    }

    // ---- Phase D: softmax + winners + upd + LN1 ----
    float lg0 = lg_s[t], lg1 = lg_s[t + 256];
    float gm = block_max(fmaxf(lg0, lg1), red4, t);
    float e0 = __expf(lg0 - gm), e1 = __expf(lg1 - gm);
    w_s[t] = e0; w_s[t + 256] = e1;
    float inv = 1.0f / block_sum(e0 + e1, red4, t);   // syncs publish w_s

    if (e0 > 0.f) { int p = atomicAdd(&cnt_s, 1); idx_s[p] = t; }
    if (e1 > 0.f) { int p = atomicAdd(&cnt_s, 1); idx_s[p] = t + 256; }
    __syncthreads();
    const int cnt = cnt_s;

    {   // snf[t] = sum_winners w_n * node_f[n, t]  (rows are L2-hot)
        float s = 0.f;
        const float* base = node_f + (size_t)(b * NPB) * 256 + t;
        for (int i = 0; i < cnt; ++i) {
            int n = idx_s[i];
            s += w_s[n] * base[(size_t)n * 256];
        }
        snf_s[t] = s;
    }
    {   // rj[j] = sum_winners w_n * rbf[n, j]  (d10 from LDS, bitwise same as C)
        int j = t & 63, g = t >> 6;
        float mu = j * MU_STEP;
        float r = 0.f;
        for (int i = g; i < cnt; i += 4) {
            int n = idx_s[i];
            float uu = (d10_s[n] - mu) * INV_SIG;
            r += w_s[n] * __expf(-uu * uu);
        }
        red[t] = r;
        __syncthreads();
        if (t < 64) rj_s[t] = red[t] + red[t + 64] + red[t + 128] + red[t + 192];
        __syncthreads();
    }

    float upd;
    {   // coalesced KT reads, 8-batched
        float u = 0.f;
        for (int c = 0; c < 256; c += 8) {
            float k8[8];
#pragma unroll
            for (int q = 0; q < 8; ++q) k8[q] = KT[(size_t)(c + q) * 256 + t];
#pragma unroll
            for (int q = 0; q < 8; ++q) u = fmaf(k8[q], snf_s[c + q], u);
        }
        float e = 0.f;
        for (int j = 0; j < 64; j += 8) {
            float k8[8];
#pragma unroll
            for (int q = 0; q < 8; ++q) k8[q] = KT[(size_t)(256 + j + q) * 256 + t];
#pragma unroll
            for (int q = 0; q < 8; ++q) e = fmaf(k8[q], rj_s[j + q], e);
        }
        upd = (u + e) * inv + bkv[256 + t];
    }

    float x    = af_s[t] + upd;
    float mean = block_sum(x, red4, t) * (1.0f / 256.0f);
    float xc   = x - mean;
    float var  = block_sum(xc * xc, red4, t) * (1.0f / 256.0f);
    af1_out[(size_t)a * 256 + t] = xc * rsqrtf(var + 1e-5f) * ln1_g[t] + ln1_b[t];
}

// ---------------------------------------------------------------------------
// K3: fused MLP (3 layers) + residual + LN2.  256 blocks x 512 threads,
// 2 anchors/block (full chip coverage); 8-batched coalesced WT loads.
// ---------------------------------------------------------------------------
__global__ void __launch_bounds__(512) mlp_fused(
    const float* __restrict__ af1,
    const float* __restrict__ W1T, const float* __restrict__ b1,
    const float* __restrict__ W2T, const float* __restrict__ b2,
    const float* __restrict__ W3T, const float* __restrict__ b3,
    const float* __restrict__ g2,  const float* __restrict__ bb2,
    float* __restrict__ out)
{
    __shared__ float af_s[2 * 256];
    __shared__ float m1_s[2 * 512];
    __shared__ float m2_s[2 * 512];
    __shared__ float red8[8];
    const int t = threadIdx.x;
    const int a0 = blockIdx.x * 2;

    if (t < 128) ((float4*)af_s)[t] = ((const float4*)(af1 + (size_t)a0 * 256))[t];
    __syncthreads();

    // ---- L1: m1[p][t] = relu(b1[t] + sum_k af[p][k]*W1T[k][t]) ----
    {
        float bv = b1[t];
        float acc0 = bv, acc1 = bv;
        const float* w = W1T + t;
        for (int k = 0; k < 256; k += 8) {
            float w8[8];
#pragma unroll
            for (int u = 0; u < 8; ++u) w8[u] = w[(size_t)(k + u) * 512];
#pragma unroll
            for (int u = 0; u < 8; ++u) {
                acc0 = fmaf(af_s[k + u],       w8[u], acc0);
                acc1 = fmaf(af_s[256 + k + u], w8[u], acc1);
            }
        }
        m1_s[t]       = fmaxf(acc0, 0.f);
        m1_s[512 + t] = fmaxf(acc1, 0.f);
    }
    __syncthreads();

    // ---- L2: m2[p][t] = relu(b2[t] + sum_k m1[p][k]*W2T[k][t]) ----
    {
        float bv = b2[t];
        float acc0 = bv, acc1 = bv;
        const float* w = W2T + t;
        for (int k = 0; k < 512; k += 8) {
            float w8[8];
#pragma unroll
            for (int u = 0; u < 8; ++u) w8[u] = w[(size_t)(k + u) * 512];
#pragma unroll
            for (int u = 0; u < 8; ++u) {
                acc0 = fmaf(m1_s[k + u],       w8[u], acc0);
                acc1 = fmaf(m1_s[512 + k + u], w8[u], acc1);
            }
        }
        m2_s[t]       = fmaxf(acc0, 0.f);
        m2_s[512 + t] = fmaxf(acc1, 0.f);
    }
    __syncthreads();

    // ---- L3 split-k halves: y[p][th] = b3 + sum_k m2[p][k]*W3T[k][th] ----
    const int th = t & 255, kh = t >> 8;
    {
        float bv = (kh == 0) ? b3[th] : 0.f;
        float p0 = bv, p1 = bv;
        const float* w = W3T + th;
        const int kb = kh * 256;
        for (int k = 0; k < 256; k += 8) {
            float w8[8];
#pragma unroll
            for (int u = 0; u < 8; ++u) w8[u] = w[(size_t)(kb + k + u) * 256];
#pragma unroll
            for (int u = 0; u < 8; ++u) {
                p0 = fmaf(m2_s[kb + k + u],       w8[u], p0);
                p1 = fmaf(m2_s[512 + kb + k + u], w8[u], p1);
            }
        }
        m1_s[t]       = p0;    // m1_s dead: reuse for partial combine
        m1_s[512 + t] = p1;
    }
    __syncthreads();

    float y[2];
    float gv = 0.f, bv2 = 0.f;
    if (kh == 0) {
#pragma unroll
        for (int p = 0; p < 2; ++p)
            y[p] = m1_s[p * 512 + th] + m1_s[p * 512 + 256 + th] + af_s[p * 256 + th];
        gv = g2[th]; bv2 = bb2[th];
    }

#pragma unroll
    for (int p = 0; p < 2; ++p) {
        float s  = block_sum512((kh == 0) ? y[p] : 0.f, red8, t);
        float mn = s * (1.0f / 256.0f);
        float yc = (kh == 0) ? (y[p] - mn) : 0.f;
        float vr = block_sum512(yc * yc, red8, t) * (1.0f / 256.0f);
        if (kh == 0)
            out[(size_t)(a0 + p) * 256 + th] = yc * rsqrtf(vr + 1e-5f) * gv + bv2;
    }
}

// ---------------------------------------------------------------------------
extern "C" void kernel_launch(void* const* d_in, const int* in_sizes, int n_in,
                              void* d_out, int out_size, void* d_ws, size_t ws_size,
                              hipStream_t stream)
{
    const float* anchor_x  = (const float*)d_in[0];
    const float* node_x    = (const float*)d_in[1];
    const float* anchor_f  = (const float*)d_in[2];
    const float* node_f    = (const float*)d_in[3];
    const float* node_mask = (const float*)d_in[6];
    const float* Wq        = (const float*)d_in[7];
    const float* bq        = (const float*)d_in[8];
    const float* Wkv       = (const float*)d_in[9];
    const float* bkv       = (const float*)d_in[10];
    const float* ln1_g     = (const float*)d_in[11];
    const float* ln1_b     = (const float*)d_in[12];
    const float* W1        = (const float*)d_in[13];
    const float* b1        = (const float*)d_in[14];
    const float* W2        = (const float*)d_in[15];
    const float* b2        = (const float*)d_in[16];
    const float* W3        = (const float*)d_in[17];
    const float* b3        = (const float*)d_in[18];
    const float* ln2_g     = (const float*)d_in[19];
    const float* ln2_b     = (const float*)d_in[20];

    float* ws   = (float*)d_ws;
    float* G    = ws + OFF_G;
    float* KT   = ws + OFF_KT;
    float* W1T  = ws + OFF_W1T;
    float* W2T  = ws + OFF_W2T;
    float* W3T  = ws + OFF_W3T;
    float* af1  = ws + OFF_AF1;

    prep_weights<<<178, 256, 0, stream>>>(Wq, bq, Wkv, bkv, W1, W2, W3,
                                          G, KT, W1T, W2T, W3T);

    attn_fused<<<NA, 256, 0, stream>>>(anchor_x, node_x, anchor_f, node_f,
                                       node_mask, G, KT, bkv, ln1_g, ln1_b, af1);

    mlp_fused<<<256, 512, 0, stream>>>(af1, W1T, b1, W2T, b2, W3T, b3,
                                       ln2_g, ln2_b, (float*)d_out);
}